// Round 14
// baseline (143.112 us; speedup 1.0000x reference)
//
#include <hip/hip_runtime.h>
#include <math.h>

#define NTOK 2304      // 48*48 tokens
#define BATCH 2
#define CIN 256
#define HID 512        // 8 heads * 64
#define NH 8
#define LOG2E 1.44269504088896340736f

typedef __attribute__((ext_vector_type(8))) short bfrag;    // 8 bf16 (4 VGPRs)
typedef __attribute__((ext_vector_type(16))) float f32x16;  // MFMA 32x32 accumulator

#if __has_builtin(__builtin_amdgcn_exp2f)
#define EXP2(x) __builtin_amdgcn_exp2f(x)
#else
#define EXP2(x) exp2f(x)
#endif

// fp32 -> bf16 (RNE)
__device__ __forceinline__ unsigned f2bf(float f) {
    unsigned u = __float_as_uint(f);
    u += 0x7FFF + ((u >> 16) & 1);
    return u >> 16;
}

__device__ __forceinline__ float bf2f(unsigned short s) {
    return __uint_as_float(((unsigned)s) << 16);
}

// pack trunc(hi(b)) , trunc(hi(a)) -> one dword {bf16(b):bf16(a)} in 1 v_perm
__device__ __forceinline__ unsigned pk_trunc(float a, float b) {
    return __builtin_amdgcn_perm(__float_as_uint(b), __float_as_uint(a), 0x07060302u);
}

// exp2 + bf16-pack + lane^32 half-swap: accS (S^T quadrant, C-layout) ->
// two A-operand P frags. Row sums are done by MFMA against a ones matrix
// (issue-bound kernel: 2 MFMA issues replace ~32 VALU instrs — R12 win).
__device__ __forceinline__ void softmax_frag(
    const f32x16& accS, int h, bfrag& P0, bfrag& P1)
{
    unsigned dw[8];
#pragma unroll
    for (int i = 0; i < 8; i++) {
        float plo = EXP2(accS[2 * i]);
        float phi = EXP2(accS[2 * i + 1]);
        dw[i] = pk_trunc(plo, phi);
    }
    unsigned sa0 = h ? dw[0] : dw[2], sb0 = h ? dw[1] : dw[3];
    unsigned sa1 = h ? dw[4] : dw[6], sb1 = h ? dw[5] : dw[7];
    unsigned ra0 = (unsigned)__shfl_xor((int)sa0, 32, 64);
    unsigned rb0 = (unsigned)__shfl_xor((int)sb0, 32, 64);
    unsigned ra1 = (unsigned)__shfl_xor((int)sa1, 32, 64);
    unsigned rb1 = (unsigned)__shfl_xor((int)sb1, 32, 64);
    union { bfrag f; unsigned u[4]; } U0, U1;
    U0.u[0] = h ? ra0 : dw[0];  U0.u[1] = h ? rb0 : dw[1];
    U0.u[2] = h ? dw[2] : ra0;  U0.u[3] = h ? dw[3] : rb0;
    U1.u[0] = h ? ra1 : dw[4];  U1.u[1] = h ? rb1 : dw[5];
    U1.u[2] = h ? dw[6] : ra1;  U1.u[3] = h ? dw[7] : rb1;
    P0 = U0.f; P1 = U1.f;
}

// ---------------------------------------------------------------------------
// Merged input pack: weights (frag-major) + x transpose-pack (frag-major).
//   bid <  288 : pack_xT tile; bid >= 288 : weights (bid 288 zeroes sumsq)
// ---------------------------------------------------------------------------
__global__ __launch_bounds__(256) void pack_all(
    const float* __restrict__ wq, short* __restrict__ wqb,
    const float* __restrict__ wp, short* __restrict__ wpb,
    const float* __restrict__ x, short* __restrict__ xT,
    float* __restrict__ sumsq)
{
    int bid = blockIdx.x;
    if (bid < 288) {
        int n0 = (bid % 36) * 64, c0 = ((bid / 36) & 3) * 64, b = bid / 144;
        __shared__ float sT[64][65];
        int tid = threadIdx.x, lane = tid & 63, wv = tid >> 6;
        for (int c = wv; c < 64; c += 4)
            sT[c][lane] = x[((size_t)b * CIN + c0 + c) * NTOK + n0 + lane];
        __syncthreads();
        int n = tid >> 2, c4 = (tid & 3) * 16;
        unsigned buf[8];
#pragma unroll
        for (int i = 0; i < 8; i++)
            buf[i] = f2bf(sT[c4 + 2 * i][n]) | (f2bf(sT[c4 + 2 * i + 1][n]) << 16);
        int n_tok = n0 + n;
        int l31n = n & 31;
        short* dst = xT + (((size_t)b * 72 + (n_tok >> 5)) * 16 + ((c0 + c4) >> 4)) * 512;
        ((uint4*)(dst + (0 * 32 + l31n) * 8))[0] = make_uint4(buf[0], buf[1], buf[2], buf[3]);
        ((uint4*)(dst + (1 * 32 + l31n) * 8))[0] = make_uint4(buf[4], buf[5], buf[6], buf[7]);
    } else {
        if (bid == 288) {
            ((float4*)sumsq)[threadIdx.x * 2] = make_float4(0.f, 0.f, 0.f, 0.f);
            ((float4*)sumsq)[threadIdx.x * 2 + 1] = make_float4(0.f, 0.f, 0.f, 0.f);
        }
        int e = ((bid - 288) * 256 + threadIdx.x) * 8;
        const int NQ = 1536 * 256;
        const float* src; short* dst;
        if (e < NQ) {
            int row = e >> 8, c = e & 255;
            int off = (((row >> 5) * 16 + (c >> 4)) * 64 + ((c >> 3) & 1) * 32 + (row & 31)) * 8;
            src = wq + e; dst = wqb + off;
        } else {
            int e2 = e - NQ;
            int row = e2 >> 9, c = e2 & 511;
            int off = (((row >> 5) * 32 + (c >> 4)) * 64 + ((c >> 3) & 1) * 32 + (row & 31)) * 8;
            src = wp + e2; dst = wpb + off;
        }
        float4 v0 = ((const float4*)src)[0];
        float4 v1 = ((const float4*)src)[1];
        unsigned b0 = f2bf(v0.x) | (f2bf(v0.y) << 16);
        unsigned b1 = f2bf(v0.z) | (f2bf(v0.w) << 16);
        unsigned b2 = f2bf(v1.x) | (f2bf(v1.y) << 16);
        unsigned b3 = f2bf(v1.z) | (f2bf(v1.w) << 16);
        *((uint4*)dst) = make_uint4(b0, b1, b2, b3);
    }
}

// ---------------------------------------------------------------------------
// QKV GEMM (MFMA): BM=128, BN=128, K=256, all operands fragment-major.
// q,k rows -> RAW bf16 qkt frag-major via coalesced uint2 stores;
// v rows -> bf16 vb frag-major. grid (18, 12, 2). (unchanged from R8-R12.)
// ---------------------------------------------------------------------------
__global__ __launch_bounds__(256, 2) void gemm_qkv(
    const short* __restrict__ A,     // wqb frag-major
    const short* __restrict__ B,     // xT frag-major
    short* __restrict__ qku,         // qkt buffer (stays raw; attn scales Q)
    short* __restrict__ vb)
{
    int b = blockIdx.z;
    int o0 = blockIdx.y * 128;
    int n0 = blockIdx.x * 128;
    int tid = threadIdx.x, wv = tid >> 6, lane = tid & 63;
    int h = lane >> 5, l31 = lane & 31;

    const short* pa = A + ((size_t)(o0 >> 5) * 16) * 512 + lane * 8;
    const short* pb = B + (((size_t)b * 72 + (n0 >> 5) + wv) * 16) * 512 + lane * 8;

    f32x16 acc[4];
#pragma unroll
    for (int rb = 0; rb < 4; rb++)
#pragma unroll
        for (int r = 0; r < 16; r++) acc[rb][r] = 0.f;

#pragma unroll 2
    for (int kc = 0; kc < 16; kc++) {
        bfrag a0 = *(const bfrag*)(pa + (size_t)(0 * 16 + kc) * 512);
        bfrag a1 = *(const bfrag*)(pa + (size_t)(1 * 16 + kc) * 512);
        bfrag a2 = *(const bfrag*)(pa + (size_t)(2 * 16 + kc) * 512);
        bfrag a3 = *(const bfrag*)(pa + (size_t)(3 * 16 + kc) * 512);
        bfrag bb = *(const bfrag*)(pb + (size_t)kc * 512);
        acc[0] = __builtin_amdgcn_mfma_f32_32x32x16_bf16(a0, bb, acc[0], 0, 0, 0);
        acc[1] = __builtin_amdgcn_mfma_f32_32x32x16_bf16(a1, bb, acc[1], 0, 0, 0);
        acc[2] = __builtin_amdgcn_mfma_f32_32x32x16_bf16(a2, bb, acc[2], 0, 0, 0);
        acc[3] = __builtin_amdgcn_mfma_f32_32x32x16_bf16(a3, bb, acc[3], 0, 0, 0);
    }

    int nn = n0 + wv * 32 + l31;
    if (o0 < 1024) {
        int sel = o0 >> 9;                       // constant per block
        short* Qb = qku + (size_t)sel * (16 * NTOK * 64);
        int oo = o0 & 511;                       // row base within sel
        int tl = nn & 31;
        size_t base_mb = (size_t)(nn >> 5) * 4;  // mb*4
#pragma unroll
        for (int rb = 0; rb < 4; rb++) {
            int hh2 = (oo + rb * 32) >> 6;
            int ihi = (rb & 1) * 2;
            short* Qbb = Qb + (size_t)(b * 8 + hh2) * (NTOK * 64);
#pragma unroll
            for (int q = 0; q < 4; q++) {
                int i = ihi + (q >> 1);
                unsigned lo = f2bf(acc[rb][4 * q])     | (f2bf(acc[rb][4 * q + 1]) << 16);
                unsigned hi = f2bf(acc[rb][4 * q + 2]) | (f2bf(acc[rb][4 * q + 3]) << 16);
                *(uint2*)(Qbb + (base_mb + i) * 512 + ((q & 1) * 32 + tl) * 8 + 4 * h)
                    = make_uint2(lo, hi);
            }
        }
    } else {
        // fragment-major V store
        short* V = vb + (size_t)b * 512 * NTOK;
        int ov = o0 - 1024;
        int mb = nn >> 5, jc = (nn >> 4) & 1, hv = (nn >> 3) & 1, e = nn & 7;
#pragma unroll
        for (int rb = 0; rb < 4; rb++)
#pragma unroll
            for (int r = 0; r < 16; r++) {
                int ml = (r & 3) + 8 * (r >> 2) + 4 * h;
                int row = ov + rb * 32 + ml;                 // 0..511
                int hh2 = row >> 6, dl = row & 63;
                int jr = dl >> 5, l31v = dl & 31;
                V[((((size_t)hh2 * 72 + mb) * 4 + jr * 2 + jc) * 64
                   + hv * 32 + l31v) * 8 + e] = (short)f2bf(acc[rb][r]);
            }
    }
}

// ---------------------------------------------------------------------------
// Per-row sum of squares from bf16 qkt (streaming). grid 1152 x 64.
// ---------------------------------------------------------------------------
__global__ __launch_bounds__(64) void sumsq_qk(
    const short* __restrict__ qkt, float* __restrict__ sumsq)
{
    int bid = blockIdx.x;
    int mc = bid % 9;
    int rest = bid / 9;
    int i = rest & 3;
    int selbh = rest >> 2;                  // 0..31
    int lane = threadIdx.x;
    const short* p = qkt + (((size_t)selbh * 72 + mc * 8) * 4 + i) * 512 + lane * 8;
    float sq[8] = {0.f, 0.f, 0.f, 0.f, 0.f, 0.f, 0.f, 0.f};
#pragma unroll
    for (int m = 0; m < 8; m++) {
        bfrag v = *(const bfrag*)(p + (size_t)m * 2048);
#pragma unroll
        for (int e = 0; e < 8; e++) {
            float f = bf2f((unsigned short)v[e]);
            sq[e] += f * f;
        }
    }
#pragma unroll
    for (int off = 1; off <= 16; off <<= 1)
#pragma unroll
        for (int e = 0; e < 8; e++)
            sq[e] += __shfl_xor(sq[e], off, 64);
    if ((lane & 31) == 0) {
        int sel = selbh >> 4, bh = selbh & 15;
        int b = bh >> 3, hh = bh & 7, hsel = lane >> 5;
        int dbase = i * 16 + hsel * 8;
        float* dst = sumsq + b * 1024 + sel * 512 + hh * 64 + dbase;
#pragma unroll
        for (int e = 0; e < 8; e++) atomicAdd(dst + e, sq[e]);
    }
}

// ---------------------------------------------------------------------------
// Attention v6 = R12's structure (1-wave blocks, grid 4608, MFMA-ones row
// sums, launch_bounds(64,2)) + FUSED Q-scale in the prologue (replaces the
// scale_q dispatch): q' = q * log2e * iq[d] * ik[d], identical rounding to
// the deleted pass. R11's regression was the (64,4) register starvation,
// fixed by (64,2) in R12. ~40 one-time VALU ops per block — negligible.
// ---------------------------------------------------------------------------
__global__ __launch_bounds__(64, 2) void attn_nb(
    const short* __restrict__ qkt,   // frag-major; q RAW, k RAW
    const short* __restrict__ vb,    // frag-major
    const float* __restrict__ sumsq, // [2048] per-row sum of squares
    short* __restrict__ Opart,       // [4 split][2][72][32][64][8] bf16
    float* __restrict__ lsum)        // [4 split][16][2304] fp32
{
    int bid = blockIdx.x;
    int x = bid & 7;                    // XCD under round-robin dispatch
    int r = bid >> 3;                   // 0..575
    int g = x * 8 + r / 72;             // (bh,ms) pair 0..63
    int nbi = r % 72;                   // 32-token n-group
    int bh = g >> 2, ms = g & 3;
    int b = bh >> 3, hh = bh & 7;
    int lane = threadIdx.x;
    int h = lane >> 5, l31 = lane & 31;
    int nb = nbi * 32;
    int mb0 = ms * 18;                  // starting 32-token m-block

    const short* Qt = qkt + (size_t)bh * NTOK * 64;
    const short* kp = qkt + (size_t)16 * NTOK * 64 + (size_t)bh * NTOK * 64
                    + ((size_t)mb0 * 4) * 512 + lane * 8;
    const short* vp = vb + (((size_t)(b * 8 + hh) * 72 + mb0) * 4) * 512 + lane * 8;

    // ---- load raw Q frags, scale by log2e * iq[d] * ik[d] (from sumsq)
    bfrag bQ[4];
    {
        const short* q0 = Qt + ((size_t)nbi * 4) * 512 + lane * 8;
        const float* sq = sumsq + b * 1024 + hh * 64;        // q rows
        const float* sk = sumsq + b * 1024 + 512 + hh * 64;  // k rows
#pragma unroll
        for (int i = 0; i < 4; i++) {
            bfrag qr = *(const bfrag*)(q0 + i * 512);
            int d0 = i * 16 + h * 8;
            float4 a0 = *(const float4*)(sq + d0);
            float4 a1 = *(const float4*)(sq + d0 + 4);
            float4 c0 = *(const float4*)(sk + d0);
            float4 c1 = *(const float4*)(sk + d0 + 4);
            float iv0 = LOG2E / (fmaxf(sqrtf(a0.x), 1e-12f) * fmaxf(sqrtf(c0.x), 1e-12f));
            float iv1 = LOG2E / (fmaxf(sqrtf(a0.y), 1e-12f) * fmaxf(sqrtf(c0.y), 1e-12f));
            float iv2 = LOG2E / (fmaxf(sqrtf(a0.z), 1e-12f) * fmaxf(sqrtf(c0.z), 1e-12f));
            float iv3 = LOG2E / (fmaxf(sqrtf(a0.w), 1e-12f) * fmaxf(sqrtf(c0.w), 1e-12f));
            float iv4 = LOG2E / (fmaxf(sqrtf(a1.x), 1e-12f) * fmaxf(sqrtf(c1.x), 1e-12f));
            float iv5 = LOG2E / (fmaxf(sqrtf(a1.y), 1e-12f) * fmaxf(sqrtf(c1.y), 1e-12f));
            float iv6 = LOG2E / (fmaxf(sqrtf(a1.z), 1e-12f) * fmaxf(sqrtf(c1.z), 1e-12f));
            float iv7 = LOG2E / (fmaxf(sqrtf(a1.w), 1e-12f) * fmaxf(sqrtf(c1.w), 1e-12f));
            union { bfrag f; unsigned short u[8]; } U;
            U.u[0] = (unsigned short)f2bf(bf2f((unsigned short)qr[0]) * iv0);
            U.u[1] = (unsigned short)f2bf(bf2f((unsigned short)qr[1]) * iv1);
            U.u[2] = (unsigned short)f2bf(bf2f((unsigned short)qr[2]) * iv2);
            U.u[3] = (unsigned short)f2bf(bf2f((unsigned short)qr[3]) * iv3);
            U.u[4] = (unsigned short)f2bf(bf2f((unsigned short)qr[4]) * iv4);
            U.u[5] = (unsigned short)f2bf(bf2f((unsigned short)qr[5]) * iv5);
            U.u[6] = (unsigned short)f2bf(bf2f((unsigned short)qr[6]) * iv6);
            U.u[7] = (unsigned short)f2bf(bf2f((unsigned short)qr[7]) * iv7);
            bQ[i] = U.f;
        }
    }

    // ones matrix fragment (bf16 1.0 everywhere — layout-independent)
    union { bfrag f; unsigned u[4]; } O1;
    O1.u[0] = 0x3F803F80u; O1.u[1] = 0x3F803F80u;
    O1.u[2] = 0x3F803F80u; O1.u[3] = 0x3F803F80u;
    bfrag ones = O1.f;

    f32x16 aL, aH, accL;
#pragma unroll
    for (int r2 = 0; r2 < 16; r2++) { aL[r2] = 0.f; aH[r2] = 0.f; accL[r2] = 0.f; }

    // prologue: load iter-0 frags
    bfrag ck[4], cv[4];
#pragma unroll
    for (int i = 0; i < 4; i++) {
        ck[i] = *(const bfrag*)(kp + i * 512);
        cv[i] = *(const bfrag*)(vp + i * 512);
    }

#pragma unroll 2
    for (int it = 0; it < 18; it++) {
        // prefetch iter t+1 (final iter reads one 4KB tile past this bh's
        // section; still inside the allocated workspace -> safe, unused)
        kp += 2048; vp += 2048;
        bfrag nk[4], nv[4];
#pragma unroll
        for (int i = 0; i < 4; i++) {
            nk[i] = *(const bfrag*)(kp + i * 512);
            nv[i] = *(const bfrag*)(vp + i * 512);
        }

        // ---- S^T, softmax -> P frags
        bfrag P0, P1;
        {
            f32x16 accS;
#pragma unroll
            for (int r2 = 0; r2 < 16; r2++) accS[r2] = 0.f;
            accS = __builtin_amdgcn_mfma_f32_32x32x16_bf16(ck[0], bQ[0], accS, 0, 0, 0);
            accS = __builtin_amdgcn_mfma_f32_32x32x16_bf16(ck[1], bQ[1], accS, 0, 0, 0);
            accS = __builtin_amdgcn_mfma_f32_32x32x16_bf16(ck[2], bQ[2], accS, 0, 0, 0);
            accS = __builtin_amdgcn_mfma_f32_32x32x16_bf16(ck[3], bQ[3], accS, 0, 0, 0);
            softmax_frag(accS, h, P0, P1);
        }
        // ---- row sums via MFMA (replaces the VALU extract+add tree)
        accL = __builtin_amdgcn_mfma_f32_32x32x16_bf16(P0, ones, accL, 0, 0, 0);
        accL = __builtin_amdgcn_mfma_f32_32x32x16_bf16(P1, ones, accL, 0, 0, 0);
        // ---- O^T += P V
        aL = __builtin_amdgcn_mfma_f32_32x32x16_bf16(P0, cv[0], aL, 0, 0, 0);
        aL = __builtin_amdgcn_mfma_f32_32x32x16_bf16(P1, cv[1], aL, 0, 0, 0);
        aH = __builtin_amdgcn_mfma_f32_32x32x16_bf16(P0, cv[2], aH, 0, 0, 0);
        aH = __builtin_amdgcn_mfma_f32_32x32x16_bf16(P1, cv[3], aH, 0, 0, 0);

        // rotate prefetched frags into current (renamed away by unroll)
#pragma unroll
        for (int i = 0; i < 4; i++) { ck[i] = nk[i]; cv[i] = nv[i]; }
    }

    // ---- row sums: accL holds S-row sums replicated across all columns.
    if (l31 == 0) {
        float* Lp = lsum + ((size_t)ms * 16 + bh) * NTOK + nb;
#pragma unroll
        for (int r2 = 0; r2 < 16; r2++) {
            int ml = (r2 & 3) + 8 * (r2 >> 2) + 4 * h;
            Lp[ml] = accL[r2];
        }
    }

    // ---- O^T partial stores (bf16, FRAGMENT-MAJOR)
    short* Ob = Opart + ((size_t)ms * 2 + b) * (72 * 32 * 64 * 8);
    int kcL = hh * 4 + (l31 >> 4);          // (k>>4) for aL (k = hh*64 + l31)
    int kcH = kcL + 2;                      // for aH (k = hh*64 + 32 + l31)
    int e = l31 & 7;
    int hs8 = ((l31 >> 3) & 1) * 32;
#pragma unroll
    for (int r2 = 0; r2 < 16; r2++) {
        int ml = (r2 & 3) + 8 * (r2 >> 2) + 4 * h;
        int wi = hs8 + ml;                  // within-slot lane index
        Ob[(((size_t)nbi * 32 + kcL) * 64 + wi) * 8 + e] = (short)f2bf(aL[r2]);
        Ob[(((size_t)nbi * 32 + kcH) * 64 + wi) * 8 + e] = (short)f2bf(aH[r2]);
    }
}

// ---------------------------------------------------------------------------
// Combine four m-splits (bf16 frag-major partials), normalize, pack bf16 aoT
// FRAGMENT-MAJOR [b][nb=72][kc=32][lane=64][8]. Fully streaming.
// grid 1152 x 256. (unchanged from R12.)
// ---------------------------------------------------------------------------
__global__ __launch_bounds__(256) void combine(
    const short* __restrict__ Opart, const float* __restrict__ lsum,
    short* __restrict__ aoT)
{
    int s = blockIdx.x * 256 + threadIdx.x;       // 0..294911
    int lane = s & 63, kc = (s >> 6) & 31, nbb = s >> 11;   // nbb = b*72+nb
    int b = nbb >= 72 ? 1 : 0, nb = nbb - 72 * b;
    int l31 = lane & 31;
    int n = nb * 32 + l31;
    int hh = kc >> 2;                              // head = k/64
    float l = 0.f;
#pragma unroll
    for (int ms = 0; ms < 4; ms++)
        l += lsum[((size_t)ms * 16 + b * 8 + hh) * NTOK + n];
    float inv = 1.f / l;
    const size_t MS = 2ull * 72 * 32 * 64 * 8;     // shorts per split
    float a[8] = {0.f, 0.f, 0.f, 0.f, 0.f, 0.f, 0.f, 0.f};
#pragma unroll
    for (int ms = 0; ms < 4; ms++) {
        uint4 v = *(const uint4*)(Opart + (size_t)ms * MS + (size_t)s * 8);
        a[0] += __uint_as_float(v.x << 16);
        a[1] += __uint_as_float(v.x & 0xffff0000u);
        a[2] += __uint_as_float(v.y << 16);
        a[3] += __uint_as_float(v.y & 0xffff0000u);
        a[4] += __uint_as_float(v.z << 16);
        a[5] += __uint_as_float(v.z & 0xffff0000u);
        a[6] += __uint_as_float(v.w << 16);
        a[7] += __uint_as_float(v.w & 0xffff0000u);
    }
    unsigned b0 = f2bf(a[0] * inv) | (f2bf(a[1] * inv) << 16);
    unsigned b1 = f2bf(a[2] * inv) | (f2bf(a[3] * inv) << 16);
    unsigned b2 = f2bf(a[4] * inv) | (f2bf(a[5] * inv) << 16);
    unsigned b3 = f2bf(a[6] * inv) | (f2bf(a[7] * inv) << 16);
    *((uint4*)(aoT + (size_t)s * 8)) = make_uint4(b0, b1, b2, b3);
}

// ---------------------------------------------------------------------------
// Proj GEMM (MFMA, frag-major operands, direct store + bias). BM=64, BN=128,
// K=512. grid (18, 4, 2). (unchanged from R12.)
// ---------------------------------------------------------------------------
__global__ __launch_bounds__(256, 2) void gemm_proj(
    const short* __restrict__ A,     // wpb frag-major [ob=8][kc=32][64][8]
    const short* __restrict__ B,     // aoT frag-major [b][nb=72][kc=32][64][8]
    const float* __restrict__ bias, float* __restrict__ y)
{
    int b = blockIdx.z;
    int o0 = blockIdx.y * 64;
    int n0 = blockIdx.x * 128;
    int tid = threadIdx.x, wv = tid >> 6, lane = tid & 63;
    int h = lane >> 5, l31 = lane & 31;

    const short* pa = A + ((size_t)(o0 >> 5) * 32) * 512 + lane * 8;
    const short* pb = B + (((size_t)b * 72 + (n0 >> 5) + wv) * 32) * 512 + lane * 8;

    f32x16 acc0, acc1;
#pragma unroll
    for (int r = 0; r < 16; r++) { acc0[r] = 0.f; acc1[r] = 0.f; }

#pragma unroll 4
    for (int kc = 0; kc < 32; kc++) {
        bfrag a0 = *(const bfrag*)(pa + (size_t)kc * 512);
        bfrag a1 = *(const bfrag*)(pa + (size_t)(32 + kc) * 512);
        bfrag bb = *(const bfrag*)(pb + (size_t)kc * 512);
        acc0 = __builtin_amdgcn_mfma_f32_32x32x16_bf16(a0, bb, acc0, 0, 0, 0);
        acc1 = __builtin_amdgcn_mfma_f32_32x32x16_bf16(a1, bb, acc1, 0, 0, 0);
    }

    int nn = n0 + wv * 32 + l31;
#pragma unroll
    for (int r = 0; r < 16; r++) {
        int ml = (r & 3) + 8 * (r >> 2) + 4 * h;
        y[((size_t)b * CIN + o0 + ml) * NTOK + nn] = acc0[r] + bias[o0 + ml];
        y[((size_t)b * CIN + o0 + 32 + ml) * NTOK + nn] = acc1[r] + bias[o0 + 32 + ml];
    }
}

// ---------------------------------------------------------------------------
// Workspace (<= 36,446,208 B of 37,748,736):
//   [0, 18,874,368)           Opart bf16 frag-major [4][2][72][32][64][8]
//                                                          (k4 -> k5)
//   [18,874,368, 23,592,960)  vb bf16 frag-major         (k2 -> k4)
//   [23,592,960, 33,030,144)  qkt bf16 frag-major RAW    (k2 -> k4);
//                              aoT overlays (k5 -> k6)
//   [33,030,144, 33,620,000~) lsum fp32 [4][16][2304]    (k4 -> k6, over dead xT)
//   [33,030,144, 35,389,440)  xT bf16 frag-major          (k1 -> k2, dead at k4)
//   [35,389,440, 36,175,872)  wqb bf16 frag-major
//   [36,175,872, 36,438,016)  wpb bf16 frag-major
//   [36,438,016, 36,446,208)  sumsq fp32 [2048]          (k1 zero, k3 acc, k4 read)
// ---------------------------------------------------------------------------
extern "C" void kernel_launch(void* const* d_in, const int* in_sizes, int n_in,
                              void* d_out, int out_size, void* d_ws, size_t ws_size,
                              hipStream_t stream)
{
    const float* x      = (const float*)d_in[0];
    const float* w_qkv  = (const float*)d_in[1];
    const float* w_proj = (const float*)d_in[2];
    const float* b_proj = (const float*)d_in[3];
    float* y = (float*)d_out;

    short* Opart = (short*)d_ws;
    short* vb    = (short*)((char*)d_ws + 18874368);
    short* qkt   = (short*)((char*)d_ws + 23592960);
    short* aoT   = (short*)((char*)d_ws + 23592960);
    float* lsum  = (float*)((char*)d_ws + 33030144);
    short* xT    = (short*)((char*)d_ws + 33030144);
    short* wqb   = (short*)((char*)d_ws + 35389440);
    short* wpb   = (short*)((char*)d_ws + 36175872);
    float* sumsq = (float*)((char*)d_ws + 36438016);

    // k1: merged pack — xT tiles + weights + sumsq=0
    pack_all<<<544, 256, 0, stream>>>(w_qkv, wqb, w_proj, wpb, x, xT, sumsq);
    // k2: QKV GEMM -> raw q,k bf16 frag-major; v frag-major
    gemm_qkv<<<dim3(NTOK / 128, 1536 / 128, BATCH), 256, 0, stream>>>(
        wqb, xT, qkt, vb);
    // k3: per-row sum of squares from bf16 qkt
    sumsq_qk<<<1152, 64, 0, stream>>>(qkt, sumsq);
    // k4: attention v6 — fused Q-scale + MFMA-ones row sums (scale_q deleted)
    attn_nb<<<4608, 64, 0, stream>>>(qkt, vb, sumsq, Opart, lsum);
    // k5: combine 4 splits (streaming) -> aoT frag-major bf16 (over dead qkt)
    combine<<<1152, 256, 0, stream>>>(Opart, lsum, aoT);
    // k6: proj GEMM, frag-major operands, direct store + bias
    gemm_proj<<<dim3(NTOK / 128, CIN / 64, BATCH), 256, 0, stream>>>(
        wpb, aoT, b_proj, y);
}

// Round 16
// 139.841 us; speedup vs baseline: 1.0234x; 1.0234x over previous
//
#include <hip/hip_runtime.h>
#include <math.h>

#define NTOK 2304      // 48*48 tokens
#define BATCH 2
#define CIN 256
#define HID 512        // 8 heads * 64
#define NH 8
#define LOG2E 1.44269504088896340736f

typedef __attribute__((ext_vector_type(8))) short bfrag;    // 8 bf16 (4 VGPRs)
typedef __attribute__((ext_vector_type(16))) float f32x16;  // MFMA 32x32 accumulator

#if __has_builtin(__builtin_amdgcn_exp2f)
#define EXP2(x) __builtin_amdgcn_exp2f(x)
#else
#define EXP2(x) exp2f(x)
#endif

// fp32 -> bf16 (RNE)
__device__ __forceinline__ unsigned f2bf(float f) {
    unsigned u = __float_as_uint(f);
    u += 0x7FFF + ((u >> 16) & 1);
    return u >> 16;
}

__device__ __forceinline__ float bf2f(unsigned short s) {
    return __uint_as_float(((unsigned)s) << 16);
}

// pack trunc(hi(b)) , trunc(hi(a)) -> one dword {bf16(b):bf16(a)} in 1 v_perm
__device__ __forceinline__ unsigned pk_trunc(float a, float b) {
    return __builtin_amdgcn_perm(__float_as_uint(b), __float_as_uint(a), 0x07060302u);
}

// exp2 + bf16-pack + lane^32 half-swap: accS (S^T quadrant, C-layout) ->
// two A-operand P frags. Row sums are done by MFMA against a ones matrix
// (issue-bound kernel: 2 MFMA issues replace ~32 VALU instrs — R12 win).
__device__ __forceinline__ void softmax_frag(
    const f32x16& accS, int h, bfrag& P0, bfrag& P1)
{
    unsigned dw[8];
#pragma unroll
    for (int i = 0; i < 8; i++) {
        float plo = EXP2(accS[2 * i]);
        float phi = EXP2(accS[2 * i + 1]);
        dw[i] = pk_trunc(plo, phi);
    }
    unsigned sa0 = h ? dw[0] : dw[2], sb0 = h ? dw[1] : dw[3];
    unsigned sa1 = h ? dw[4] : dw[6], sb1 = h ? dw[5] : dw[7];
    unsigned ra0 = (unsigned)__shfl_xor((int)sa0, 32, 64);
    unsigned rb0 = (unsigned)__shfl_xor((int)sb0, 32, 64);
    unsigned ra1 = (unsigned)__shfl_xor((int)sa1, 32, 64);
    unsigned rb1 = (unsigned)__shfl_xor((int)sb1, 32, 64);
    union { bfrag f; unsigned u[4]; } U0, U1;
    U0.u[0] = h ? ra0 : dw[0];  U0.u[1] = h ? rb0 : dw[1];
    U0.u[2] = h ? dw[2] : ra0;  U0.u[3] = h ? dw[3] : rb0;
    U1.u[0] = h ? ra1 : dw[4];  U1.u[1] = h ? rb1 : dw[5];
    U1.u[2] = h ? dw[6] : ra1;  U1.u[3] = h ? dw[7] : rb1;
    P0 = U0.f; P1 = U1.f;
}

// ---------------------------------------------------------------------------
// Merged input pack: weights (frag-major) + x transpose-pack (frag-major).
//   bid <  288 : pack_xT tile; bid >= 288 : weights (bid 288 zeroes sumsq)
// ---------------------------------------------------------------------------
__global__ __launch_bounds__(256) void pack_all(
    const float* __restrict__ wq, short* __restrict__ wqb,
    const float* __restrict__ wp, short* __restrict__ wpb,
    const float* __restrict__ x, short* __restrict__ xT,
    float* __restrict__ sumsq)
{
    int bid = blockIdx.x;
    if (bid < 288) {
        int n0 = (bid % 36) * 64, c0 = ((bid / 36) & 3) * 64, b = bid / 144;
        __shared__ float sT[64][65];
        int tid = threadIdx.x, lane = tid & 63, wv = tid >> 6;
        for (int c = wv; c < 64; c += 4)
            sT[c][lane] = x[((size_t)b * CIN + c0 + c) * NTOK + n0 + lane];
        __syncthreads();
        int n = tid >> 2, c4 = (tid & 3) * 16;
        unsigned buf[8];
#pragma unroll
        for (int i = 0; i < 8; i++)
            buf[i] = f2bf(sT[c4 + 2 * i][n]) | (f2bf(sT[c4 + 2 * i + 1][n]) << 16);
        int n_tok = n0 + n;
        int l31n = n & 31;
        short* dst = xT + (((size_t)b * 72 + (n_tok >> 5)) * 16 + ((c0 + c4) >> 4)) * 512;
        ((uint4*)(dst + (0 * 32 + l31n) * 8))[0] = make_uint4(buf[0], buf[1], buf[2], buf[3]);
        ((uint4*)(dst + (1 * 32 + l31n) * 8))[0] = make_uint4(buf[4], buf[5], buf[6], buf[7]);
    } else {
        if (bid == 288) {
            ((float4*)sumsq)[threadIdx.x * 2] = make_float4(0.f, 0.f, 0.f, 0.f);
            ((float4*)sumsq)[threadIdx.x * 2 + 1] = make_float4(0.f, 0.f, 0.f, 0.f);
        }
        int e = ((bid - 288) * 256 + threadIdx.x) * 8;
        const int NQ = 1536 * 256;
        const float* src; short* dst;
        if (e < NQ) {
            int row = e >> 8, c = e & 255;
            int off = (((row >> 5) * 16 + (c >> 4)) * 64 + ((c >> 3) & 1) * 32 + (row & 31)) * 8;
            src = wq + e; dst = wqb + off;
        } else {
            int e2 = e - NQ;
            int row = e2 >> 9, c = e2 & 511;
            int off = (((row >> 5) * 32 + (c >> 4)) * 64 + ((c >> 3) & 1) * 32 + (row & 31)) * 8;
            src = wp + e2; dst = wpb + off;
        }
        float4 v0 = ((const float4*)src)[0];
        float4 v1 = ((const float4*)src)[1];
        unsigned b0 = f2bf(v0.x) | (f2bf(v0.y) << 16);
        unsigned b1 = f2bf(v0.z) | (f2bf(v0.w) << 16);
        unsigned b2 = f2bf(v1.x) | (f2bf(v1.y) << 16);
        unsigned b3 = f2bf(v1.z) | (f2bf(v1.w) << 16);
        *((uint4*)dst) = make_uint4(b0, b1, b2, b3);
    }
}

// ---------------------------------------------------------------------------
// QKV GEMM (MFMA): BM=128, BN=128, K=256, all operands fragment-major.
// q,k rows -> RAW bf16 qkt frag-major via coalesced uint2 stores;
// v rows -> bf16 vb frag-major. grid (18, 12, 2).
// ---------------------------------------------------------------------------
__global__ __launch_bounds__(256, 2) void gemm_qkv(
    const short* __restrict__ A,     // wqb frag-major
    const short* __restrict__ B,     // xT frag-major
    short* __restrict__ qku,         // qkt buffer (unnormalized at this stage)
    short* __restrict__ vb)
{
    int b = blockIdx.z;
    int o0 = blockIdx.y * 128;
    int n0 = blockIdx.x * 128;
    int tid = threadIdx.x, wv = tid >> 6, lane = tid & 63;
    int h = lane >> 5, l31 = lane & 31;

    const short* pa = A + ((size_t)(o0 >> 5) * 16) * 512 + lane * 8;
    const short* pb = B + (((size_t)b * 72 + (n0 >> 5) + wv) * 16) * 512 + lane * 8;

    f32x16 acc[4];
#pragma unroll
    for (int rb = 0; rb < 4; rb++)
#pragma unroll
        for (int r = 0; r < 16; r++) acc[rb][r] = 0.f;

#pragma unroll 2
    for (int kc = 0; kc < 16; kc++) {
        bfrag a0 = *(const bfrag*)(pa + (size_t)(0 * 16 + kc) * 512);
        bfrag a1 = *(const bfrag*)(pa + (size_t)(1 * 16 + kc) * 512);
        bfrag a2 = *(const bfrag*)(pa + (size_t)(2 * 16 + kc) * 512);
        bfrag a3 = *(const bfrag*)(pa + (size_t)(3 * 16 + kc) * 512);
        bfrag bb = *(const bfrag*)(pb + (size_t)kc * 512);
        acc[0] = __builtin_amdgcn_mfma_f32_32x32x16_bf16(a0, bb, acc[0], 0, 0, 0);
        acc[1] = __builtin_amdgcn_mfma_f32_32x32x16_bf16(a1, bb, acc[1], 0, 0, 0);
        acc[2] = __builtin_amdgcn_mfma_f32_32x32x16_bf16(a2, bb, acc[2], 0, 0, 0);
        acc[3] = __builtin_amdgcn_mfma_f32_32x32x16_bf16(a3, bb, acc[3], 0, 0, 0);
    }

    int nn = n0 + wv * 32 + l31;
    if (o0 < 1024) {
        int sel = o0 >> 9;                       // constant per block
        short* Qb = qku + (size_t)sel * (16 * NTOK * 64);
        int oo = o0 & 511;                       // row base within sel
        int tl = nn & 31;
        size_t base_mb = (size_t)(nn >> 5) * 4;  // mb*4
#pragma unroll
        for (int rb = 0; rb < 4; rb++) {
            int hh2 = (oo + rb * 32) >> 6;
            int ihi = (rb & 1) * 2;
            short* Qbb = Qb + (size_t)(b * 8 + hh2) * (NTOK * 64);
#pragma unroll
            for (int q = 0; q < 4; q++) {
                int i = ihi + (q >> 1);
                unsigned lo = f2bf(acc[rb][4 * q])     | (f2bf(acc[rb][4 * q + 1]) << 16);
                unsigned hi = f2bf(acc[rb][4 * q + 2]) | (f2bf(acc[rb][4 * q + 3]) << 16);
                *(uint2*)(Qbb + (base_mb + i) * 512 + ((q & 1) * 32 + tl) * 8 + 4 * h)
                    = make_uint2(lo, hi);
            }
        }
    } else {
        // fragment-major V store
        short* V = vb + (size_t)b * 512 * NTOK;
        int ov = o0 - 1024;
        int mb = nn >> 5, jc = (nn >> 4) & 1, hv = (nn >> 3) & 1, e = nn & 7;
#pragma unroll
        for (int rb = 0; rb < 4; rb++)
#pragma unroll
            for (int r = 0; r < 16; r++) {
                int ml = (r & 3) + 8 * (r >> 2) + 4 * h;
                int row = ov + rb * 32 + ml;                 // 0..511
                int hh2 = row >> 6, dl = row & 63;
                int jr = dl >> 5, l31v = dl & 31;
                V[((((size_t)hh2 * 72 + mb) * 4 + jr * 2 + jc) * 64
                   + hv * 32 + l31v) * 8 + e] = (short)f2bf(acc[rb][r]);
            }
    }
}

// ---------------------------------------------------------------------------
// Per-row sum of squares from bf16 qkt (streaming). grid 1152 x 64.
// ---------------------------------------------------------------------------
__global__ __launch_bounds__(64) void sumsq_qk(
    const short* __restrict__ qkt, float* __restrict__ sumsq)
{
    int bid = blockIdx.x;
    int mc = bid % 9;
    int rest = bid / 9;
    int i = rest & 3;
    int selbh = rest >> 2;                  // 0..31
    int lane = threadIdx.x;
    const short* p = qkt + (((size_t)selbh * 72 + mc * 8) * 4 + i) * 512 + lane * 8;
    float sq[8] = {0.f, 0.f, 0.f, 0.f, 0.f, 0.f, 0.f, 0.f};
#pragma unroll
    for (int m = 0; m < 8; m++) {
        bfrag v = *(const bfrag*)(p + (size_t)m * 2048);
#pragma unroll
        for (int e = 0; e < 8; e++) {
            float f = bf2f((unsigned short)v[e]);
            sq[e] += f * f;
        }
    }
#pragma unroll
    for (int off = 1; off <= 16; off <<= 1)
#pragma unroll
        for (int e = 0; e < 8; e++)
            sq[e] += __shfl_xor(sq[e], off, 64);
    if ((lane & 31) == 0) {
        int sel = selbh >> 4, bh = selbh & 15;
        int b = bh >> 3, hh = bh & 7, hsel = lane >> 5;
        int dbase = i * 16 + hsel * 8;
        float* dst = sumsq + b * 1024 + sel * 512 + hh * 64 + dbase;
#pragma unroll
        for (int e = 0; e < 8; e++) atomicAdd(dst + e, sq[e]);
    }
}

// ---------------------------------------------------------------------------
// Q-ONLY scale: both inverse norms + log2e fold into Q; K stays RAW.
// grid 1152 x 256. (Standalone pass — fusing it into attn was falsified
// twice: the compiler's VGPR allocation collapses to 56-68 and breaks the
// prefetch pipeline, +10-13us. R11/R14.)
// ---------------------------------------------------------------------------
__global__ __launch_bounds__(256) void scale_q(
    short* __restrict__ qkt, const float* __restrict__ sumsq)
{
    int s = blockIdx.x * 256 + threadIdx.x;       // q frag slot, 0..294911
    int lane = s & 63;
    int rest = s >> 6;
    int fi = rest & 3;
    int bh = rest / 288;                          // 0..15
    int b = bh >> 3, hh = bh & 7;
    int d0 = fi * 16 + (lane >> 5) * 8;
    const float* sq = sumsq + b * 1024 + hh * 64 + d0;        // q rows
    const float* sk = sumsq + b * 1024 + 512 + hh * 64 + d0;  // k rows
    float4 q0 = ((const float4*)sq)[0], q1 = ((const float4*)sq)[1];
    float4 k0 = ((const float4*)sk)[0], k1 = ((const float4*)sk)[1];
    float i0 = LOG2E / (fmaxf(sqrtf(q0.x), 1e-12f) * fmaxf(sqrtf(k0.x), 1e-12f));
    float i1 = LOG2E / (fmaxf(sqrtf(q0.y), 1e-12f) * fmaxf(sqrtf(k0.y), 1e-12f));
    float i2 = LOG2E / (fmaxf(sqrtf(q0.z), 1e-12f) * fmaxf(sqrtf(k0.z), 1e-12f));
    float i3 = LOG2E / (fmaxf(sqrtf(q0.w), 1e-12f) * fmaxf(sqrtf(k0.w), 1e-12f));
    float i4 = LOG2E / (fmaxf(sqrtf(q1.x), 1e-12f) * fmaxf(sqrtf(k1.x), 1e-12f));
    float i5 = LOG2E / (fmaxf(sqrtf(q1.y), 1e-12f) * fmaxf(sqrtf(k1.y), 1e-12f));
    float i6 = LOG2E / (fmaxf(sqrtf(q1.z), 1e-12f) * fmaxf(sqrtf(k1.z), 1e-12f));
    float i7 = LOG2E / (fmaxf(sqrtf(q1.w), 1e-12f) * fmaxf(sqrtf(k1.w), 1e-12f));
    uint4 v = ((uint4*)qkt)[s];
    unsigned o0w = f2bf(__uint_as_float(v.x << 16) * i0)
                 | (f2bf(__uint_as_float(v.x & 0xffff0000u) * i1) << 16);
    unsigned o1w = f2bf(__uint_as_float(v.y << 16) * i2)
                 | (f2bf(__uint_as_float(v.y & 0xffff0000u) * i3) << 16);
    unsigned o2w = f2bf(__uint_as_float(v.z << 16) * i4)
                 | (f2bf(__uint_as_float(v.z & 0xffff0000u) * i5) << 16);
    unsigned o3w = f2bf(__uint_as_float(v.w << 16) * i6)
                 | (f2bf(__uint_as_float(v.w & 0xffff0000u) * i7) << 16);
    ((uint4*)qkt)[s] = make_uint4(o0w, o1w, o2w, o3w);
}

// ---------------------------------------------------------------------------
// Attention v5 (R12, best measured): 1-wave blocks, grid 4608, no barrier,
// no LDS, pre-scaled Q, register prefetch, MFMA-ones row sums,
// launch_bounds(64,2) so the compiler keeps the prefetch pipeline's VGPRs.
// ---------------------------------------------------------------------------
__global__ __launch_bounds__(64, 2) void attn_nb(
    const short* __restrict__ qkt,   // frag-major; q pre-scaled, k RAW
    const short* __restrict__ vb,    // frag-major
    short* __restrict__ Opart,       // [4 split][2][72][32][64][8] bf16
    float* __restrict__ lsum)        // [4 split][16][2304] fp32
{
    int bid = blockIdx.x;
    int x = bid & 7;                    // XCD under round-robin dispatch
    int r = bid >> 3;                   // 0..575
    int g = x * 8 + r / 72;             // (bh,ms) pair 0..63
    int nbi = r % 72;                   // 32-token n-group
    int bh = g >> 2, ms = g & 3;
    int b = bh >> 3, hh = bh & 7;
    int lane = threadIdx.x;
    int h = lane >> 5, l31 = lane & 31;
    int nb = nbi * 32;
    int mb0 = ms * 18;                  // starting 32-token m-block

    const short* Qt = qkt + (size_t)bh * NTOK * 64;
    const short* kp = qkt + (size_t)16 * NTOK * 64 + (size_t)bh * NTOK * 64
                    + ((size_t)mb0 * 4) * 512 + lane * 8;
    const short* vp = vb + (((size_t)(b * 8 + hh) * 72 + mb0) * 4) * 512 + lane * 8;

    bfrag bQ[4];
    {
        const short* q0 = Qt + ((size_t)nbi * 4) * 512 + lane * 8;
#pragma unroll
        for (int i = 0; i < 4; i++) bQ[i] = *(const bfrag*)(q0 + i * 512);
    }

    // ones matrix fragment (bf16 1.0 everywhere — layout-independent)
    union { bfrag f; unsigned u[4]; } O1;
    O1.u[0] = 0x3F803F80u; O1.u[1] = 0x3F803F80u;
    O1.u[2] = 0x3F803F80u; O1.u[3] = 0x3F803F80u;
    bfrag ones = O1.f;

    f32x16 aL, aH, accL;
#pragma unroll
    for (int r2 = 0; r2 < 16; r2++) { aL[r2] = 0.f; aH[r2] = 0.f; accL[r2] = 0.f; }

    // prologue: load iter-0 frags
    bfrag ck[4], cv[4];
#pragma unroll
    for (int i = 0; i < 4; i++) {
        ck[i] = *(const bfrag*)(kp + i * 512);
        cv[i] = *(const bfrag*)(vp + i * 512);
    }

#pragma unroll 2
    for (int it = 0; it < 18; it++) {
        // prefetch iter t+1 (final iter reads one 4KB tile past this bh's
        // section; still inside the allocated workspace -> safe, unused)
        kp += 2048; vp += 2048;
        bfrag nk[4], nv[4];
#pragma unroll
        for (int i = 0; i < 4; i++) {
            nk[i] = *(const bfrag*)(kp + i * 512);
            nv[i] = *(const bfrag*)(vp + i * 512);
        }

        // ---- S^T, softmax -> P frags
        bfrag P0, P1;
        {
            f32x16 accS;
#pragma unroll
            for (int r2 = 0; r2 < 16; r2++) accS[r2] = 0.f;
            accS = __builtin_amdgcn_mfma_f32_32x32x16_bf16(ck[0], bQ[0], accS, 0, 0, 0);
            accS = __builtin_amdgcn_mfma_f32_32x32x16_bf16(ck[1], bQ[1], accS, 0, 0, 0);
            accS = __builtin_amdgcn_mfma_f32_32x32x16_bf16(ck[2], bQ[2], accS, 0, 0, 0);
            accS = __builtin_amdgcn_mfma_f32_32x32x16_bf16(ck[3], bQ[3], accS, 0, 0, 0);
            softmax_frag(accS, h, P0, P1);
        }
        // ---- row sums via MFMA (replaces the VALU extract+add tree)
        accL = __builtin_amdgcn_mfma_f32_32x32x16_bf16(P0, ones, accL, 0, 0, 0);
        accL = __builtin_amdgcn_mfma_f32_32x32x16_bf16(P1, ones, accL, 0, 0, 0);
        // ---- O^T += P V
        aL = __builtin_amdgcn_mfma_f32_32x32x16_bf16(P0, cv[0], aL, 0, 0, 0);
        aL = __builtin_amdgcn_mfma_f32_32x32x16_bf16(P1, cv[1], aL, 0, 0, 0);
        aH = __builtin_amdgcn_mfma_f32_32x32x16_bf16(P0, cv[2], aH, 0, 0, 0);
        aH = __builtin_amdgcn_mfma_f32_32x32x16_bf16(P1, cv[3], aH, 0, 0, 0);

        // rotate prefetched frags into current (renamed away by unroll)
#pragma unroll
        for (int i = 0; i < 4; i++) { ck[i] = nk[i]; cv[i] = nv[i]; }
    }

    // ---- row sums: accL holds S-row sums replicated across all columns.
    if (l31 == 0) {
        float* Lp = lsum + ((size_t)ms * 16 + bh) * NTOK + nb;
#pragma unroll
        for (int r2 = 0; r2 < 16; r2++) {
            int ml = (r2 & 3) + 8 * (r2 >> 2) + 4 * h;
            Lp[ml] = accL[r2];
        }
    }

    // ---- O^T partial stores (bf16, FRAGMENT-MAJOR)
    short* Ob = Opart + ((size_t)ms * 2 + b) * (72 * 32 * 64 * 8);
    int kcL = hh * 4 + (l31 >> 4);          // (k>>4) for aL (k = hh*64 + l31)
    int kcH = kcL + 2;                      // for aH (k = hh*64 + 32 + l31)
    int e = l31 & 7;
    int hs8 = ((l31 >> 3) & 1) * 32;
#pragma unroll
    for (int r2 = 0; r2 < 16; r2++) {
        int ml = (r2 & 3) + 8 * (r2 >> 2) + 4 * h;
        int wi = hs8 + ml;                  // within-slot lane index
        Ob[(((size_t)nbi * 32 + kcL) * 64 + wi) * 8 + e] = (short)f2bf(aL[r2]);
        Ob[(((size_t)nbi * 32 + kcH) * 64 + wi) * 8 + e] = (short)f2bf(aH[r2]);
    }
}

// ---------------------------------------------------------------------------
// Combine four m-splits (bf16 frag-major partials), normalize, pack bf16 aoT
// FRAGMENT-MAJOR [b][nb=72][kc=32][lane=64][8]. Fully streaming.
// grid 1152 x 256.
// ---------------------------------------------------------------------------
__global__ __launch_bounds__(256) void combine(
    const short* __restrict__ Opart, const float* __restrict__ lsum,
    short* __restrict__ aoT)
{
    int s = blockIdx.x * 256 + threadIdx.x;       // 0..294911
    int lane = s & 63, kc = (s >> 6) & 31, nbb = s >> 11;   // nbb = b*72+nb
    int b = nbb >= 72 ? 1 : 0, nb = nbb - 72 * b;
    int l31 = lane & 31;
    int n = nb * 32 + l31;
    int hh = kc >> 2;                              // head = k/64
    float l = 0.f;
#pragma unroll
    for (int ms = 0; ms < 4; ms++)
        l += lsum[((size_t)ms * 16 + b * 8 + hh) * NTOK + n];
    float inv = 1.f / l;
    const size_t MS = 2ull * 72 * 32 * 64 * 8;     // shorts per split
    float a[8] = {0.f, 0.f, 0.f, 0.f, 0.f, 0.f, 0.f, 0.f};
#pragma unroll
    for (int ms = 0; ms < 4; ms++) {
        uint4 v = *(const uint4*)(Opart + (size_t)ms * MS + (size_t)s * 8);
        a[0] += __uint_as_float(v.x << 16);
        a[1] += __uint_as_float(v.x & 0xffff0000u);
        a[2] += __uint_as_float(v.y << 16);
        a[3] += __uint_as_float(v.y & 0xffff0000u);
        a[4] += __uint_as_float(v.z << 16);
        a[5] += __uint_as_float(v.z & 0xffff0000u);
        a[6] += __uint_as_float(v.w << 16);
        a[7] += __uint_as_float(v.w & 0xffff0000u);
    }
    unsigned b0 = f2bf(a[0] * inv) | (f2bf(a[1] * inv) << 16);
    unsigned b1 = f2bf(a[2] * inv) | (f2bf(a[3] * inv) << 16);
    unsigned b2 = f2bf(a[4] * inv) | (f2bf(a[5] * inv) << 16);
    unsigned b3 = f2bf(a[6] * inv) | (f2bf(a[7] * inv) << 16);
    *((uint4*)(aoT + (size_t)s * 8)) = make_uint4(b0, b1, b2, b3);
}

// ---------------------------------------------------------------------------
// Proj GEMM (MFMA, frag-major operands, direct store + bias). BM=64, BN=128,
// K=512. grid (18, 4, 2).
// ---------------------------------------------------------------------------
__global__ __launch_bounds__(256, 2) void gemm_proj(
    const short* __restrict__ A,     // wpb frag-major [ob=8][kc=32][64][8]
    const short* __restrict__ B,     // aoT frag-major [b][nb=72][kc=32][64][8]
    const float* __restrict__ bias, float* __restrict__ y)
{
    int b = blockIdx.z;
    int o0 = blockIdx.y * 64;
    int n0 = blockIdx.x * 128;
    int tid = threadIdx.x, wv = tid >> 6, lane = tid & 63;
    int h = lane >> 5, l31 = lane & 31;

    const short* pa = A + ((size_t)(o0 >> 5) * 32) * 512 + lane * 8;
    const short* pb = B + (((size_t)b * 72 + (n0 >> 5) + wv) * 32) * 512 + lane * 8;

    f32x16 acc0, acc1;
#pragma unroll
    for (int r = 0; r < 16; r++) { acc0[r] = 0.f; acc1[r] = 0.f; }

#pragma unroll 4
    for (int kc = 0; kc < 32; kc++) {
        bfrag a0 = *(const bfrag*)(pa + (size_t)kc * 512);
        bfrag a1 = *(const bfrag*)(pa + (size_t)(32 + kc) * 512);
        bfrag bb = *(const bfrag*)(pb + (size_t)kc * 512);
        acc0 = __builtin_amdgcn_mfma_f32_32x32x16_bf16(a0, bb, acc0, 0, 0, 0);
        acc1 = __builtin_amdgcn_mfma_f32_32x32x16_bf16(a1, bb, acc1, 0, 0, 0);
    }

    int nn = n0 + wv * 32 + l31;
#pragma unroll
    for (int r = 0; r < 16; r++) {
        int ml = (r & 3) + 8 * (r >> 2) + 4 * h;
        y[((size_t)b * CIN + o0 + ml) * NTOK + nn] = acc0[r] + bias[o0 + ml];
        y[((size_t)b * CIN + o0 + 32 + ml) * NTOK + nn] = acc1[r] + bias[o0 + 32 + ml];
    }
}

// ---------------------------------------------------------------------------
// Workspace (<= 36,446,208 B of 37,748,736):
//   [0, 18,874,368)           Opart bf16 frag-major [4][2][72][32][64][8]
//                                                          (k5 -> k6)
//   [18,874,368, 23,592,960)  vb bf16 frag-major         (k2 -> k5)
//   [23,592,960, 33,030,144)  qkt bf16 frag-major        (k2 -> k5; q scaled
//                              in place k4, k stays raw); aoT overlays (k6->k7)
//   [33,030,144, 33,620,000~) lsum fp32 [4][16][2304]    (k5 -> k6, over dead xT)
//   [33,030,144, 35,389,440)  xT bf16 frag-major          (k1 -> k2, dead at k5)
//   [35,389,440, 36,175,872)  wqb bf16 frag-major
//   [36,175,872, 36,438,016)  wpb bf16 frag-major
//   [36,438,016, 36,446,208)  sumsq fp32 [2048]          (k1 zero, k3 acc, k4 read)
// ---------------------------------------------------------------------------
extern "C" void kernel_launch(void* const* d_in, const int* in_sizes, int n_in,
                              void* d_out, int out_size, void* d_ws, size_t ws_size,
                              hipStream_t stream)
{
    const float* x      = (const float*)d_in[0];
    const float* w_qkv  = (const float*)d_in[1];
    const float* w_proj = (const float*)d_in[2];
    const float* b_proj = (const float*)d_in[3];
    float* y = (float*)d_out;

    short* Opart = (short*)d_ws;
    short* vb    = (short*)((char*)d_ws + 18874368);
    short* qkt   = (short*)((char*)d_ws + 23592960);
    short* aoT   = (short*)((char*)d_ws + 23592960);
    float* lsum  = (float*)((char*)d_ws + 33030144);
    short* xT    = (short*)((char*)d_ws + 33030144);
    short* wqb   = (short*)((char*)d_ws + 35389440);
    short* wpb   = (short*)((char*)d_ws + 36175872);
    float* sumsq = (float*)((char*)d_ws + 36438016);

    // k1: merged pack — xT tiles + weights + sumsq=0
    pack_all<<<544, 256, 0, stream>>>(w_qkv, wqb, w_proj, wpb, x, xT, sumsq);
    // k2: QKV GEMM -> raw q,k bf16 frag-major; v frag-major
    gemm_qkv<<<dim3(NTOK / 128, 1536 / 128, BATCH), 256, 0, stream>>>(
        wqb, xT, qkt, vb);
    // k3: per-row sum of squares from bf16 qkt
    sumsq_qk<<<1152, 64, 0, stream>>>(qkt, sumsq);
    // k4: Q-only scale (folds iq*ik*log2e into q; k stays raw)
    scale_q<<<1152, 256, 0, stream>>>(qkt, sumsq);
    // k5: attention v5 — fine-grain grid + MFMA-ones row sums
    attn_nb<<<4608, 64, 0, stream>>>(qkt, vb, Opart, lsum);
    // k6: combine 4 splits (streaming) -> aoT frag-major bf16 (over dead qkt)
    combine<<<1152, 256, 0, stream>>>(Opart, lsum, aoT);
    // k7: proj GEMM, frag-major operands, direct store + bias
    gemm_proj<<<dim3(NTOK / 128, CIN / 64, BATCH), 256, 0, stream>>>(
        wpb, aoT, b_proj, y);
}